// Round 1
// baseline (8907.114 us; speedup 1.0000x reference)
//
#include <hip/hip_runtime.h>
#include <hip/hip_bf16.h>
#include <cstdint>

// Problem dims
#define NB   256   // batch
#define NT   128   // time steps
#define NSER 128   // input series (N)
#define NH   256   // hidden (H)
#define NWG  256
#define NTHR 512

// ws layout (float offsets)
#define WS_H    0        // h double buffer [2][256][256]
#define WS_C    131072   // c double buffer [2][256][256]
#define WS_WX   262144   // wx [256][128]
#define WS_CTRL 294912   // barrier control (uints): cnt[8]@stride64, root@512, flag@576

struct __align__(16) SmemT {
  float WB[32][384];        // 48KB: gate rows [gate*8+kk][c] (c<128: W_ih, else W_hh)
  float h_s[32][260];       // staged h tile (pad 260 for bank spread)
  float wx_s[32][132];      // staged wx tile (pad 132)
  float hc[512];            // [h(256), c(256)] of this wg's batch element
  float part4[4][128];      // 4-way reduce scratch
  float P[128];             // exp(2*hpart[t'])
  float En[128];            // exp(2*ipart[n])
  float score[128];
  float gpart[2][32][8][4]; // [half][b2][kk][gate]
  float red[4];
};

__device__ __forceinline__ void gridbar(unsigned* ctrl, unsigned epoch) {
  __syncthreads();
  if (threadIdx.x == 0) {
    unsigned* cnt  = ctrl + (blockIdx.x & 7) * 64;   // 8 counters, 256B apart
    unsigned* root = ctrl + 512;
    unsigned* flag = ctrl + 576;
    unsigned a = __hip_atomic_fetch_add(cnt, 1u, __ATOMIC_ACQ_REL, __HIP_MEMORY_SCOPE_AGENT) + 1u;
    if (a == 32u * epoch) {
      unsigned r = __hip_atomic_fetch_add(root, 1u, __ATOMIC_ACQ_REL, __HIP_MEMORY_SCOPE_AGENT) + 1u;
      if (r == 8u * epoch) {
        __hip_atomic_store(flag, epoch, __ATOMIC_RELEASE, __HIP_MEMORY_SCOPE_AGENT);
      }
    }
    while (__hip_atomic_load(flag, __ATOMIC_ACQUIRE, __HIP_MEMORY_SCOPE_AGENT) < epoch) {
      __builtin_amdgcn_s_sleep(4);
    }
  }
  __syncthreads();
}

__global__ void enc_init(float* ws) {
  int i = blockIdx.x * blockDim.x + threadIdx.x;  // grid covers 65536
  if (i < 65536) {                // zero h,c parity-0
    ws[WS_H + i] = 0.f;
    ws[WS_C + i] = 0.f;
  }
  if (i < 640) ((unsigned*)(ws + WS_CTRL))[i] = 0u;
}

__global__ __launch_bounds__(NTHR, 2) void enc_main(
    const float* __restrict__ x,    const float* __restrict__ W_ah,
    const float* __restrict__ b_ah, const float* __restrict__ W_ai,
    const float* __restrict__ b_ai, const float* __restrict__ W_a,
    const float* __restrict__ b_a,  const float* __restrict__ W_ih,
    const float* __restrict__ W_hh, const float* __restrict__ b_ih,
    const float* __restrict__ b_hh, float* __restrict__ out_iw,
    float* __restrict__ out_ie,     float* __restrict__ ws)
{
  __shared__ SmemT sm;
  const int tid = threadIdx.x;
  const int wg  = blockIdx.x;
  const int b   = wg;                  // phase A batch element
  const int btile = wg & 7, ktile = wg >> 3;
  const int base_b = btile * 32;       // phase B batch base (32 b's)
  const int k0 = ktile * 8;            // phase B hidden-unit base (8 k's)

  float* hbuf  = ws + WS_H;
  float* cbuf  = ws + WS_C;
  float* wxbuf = ws + WS_WX;
  unsigned* ctrl = (unsigned*)(ws + WS_CTRL);

  const int tp = tid & 127;            // t' (hpart) / n (score)
  const int q  = tid >> 7;             // 0..3: k-quarter / t'-quarter

  // ---- startup: W_ah slice into registers (row tp, cols q*128..q*128+127) ----
  float wreg[128];
  {
    const float4* src = (const float4*)(W_ah + tp * 512 + q * 128);
    #pragma unroll
    for (int j = 0; j < 32; ++j) {
      float4 v = src[j];
      wreg[4*j] = v.x; wreg[4*j+1] = v.y; wreg[4*j+2] = v.z; wreg[4*j+3] = v.w;
    }
  }
  float w2a_r[32];
  #pragma unroll
  for (int i = 0; i < 32; ++i) w2a_r[i] = 2.f * W_a[q * 32 + i];
  const float bah_r = (q == 0) ? b_ah[tp] : 0.f;
  float S0;
  { float s = b_a[0]; for (int i = 0; i < 128; ++i) s += W_a[i]; S0 = s; }

  // phase B per-thread constants
  const int b2 = tid & 31, kk = (tid >> 5) & 7, half = tid >> 8;
  float bsum4[4];
  #pragma unroll
  for (int g = 0; g < 4; ++g) {
    int row = g * 256 + k0 + kk;
    bsum4[g] = b_ih[row] + b_hh[row];
  }

  // ---- stage this wg's W_ih/W_hh slice into LDS (once) ----
  for (int el = tid; el < 32 * 384; el += NTHR) {
    int r = el / 384, c = el % 384;
    int row = (r >> 3) * 256 + k0 + (r & 7);
    ((float*)sm.WB)[el] = (c < 128) ? W_ih[row * 128 + c] : W_hh[row * 256 + (c - 128)];
  }

  // ---- ipart -> En (time-invariant) ----
  {
    float acc = 0.f;
    const float* xb = x + b * (NT * NSER);
    for (int tt = q * 32; tt < q * 32 + 32; ++tt)
      acc += xb[tt * NSER + tp] * W_ai[tt];
    sm.part4[q][tp] = acc;
  }
  __syncthreads();
  if (tid < 128) {
    float ip = sm.part4[0][tid] + sm.part4[1][tid] + sm.part4[2][tid] + sm.part4[3][tid] + b_ai[0];
    sm.En[tid] = __expf(2.f * ip);
  }
  __syncthreads();
  const float e_r = sm.En[tp];

  unsigned ep = 1;
  for (int t = 0; t < NT; ++t) {
    const int p = t & 1, p2 = p ^ 1;

    // ================= Phase A: attention for batch b =================
    sm.hc[tid] = (tid < 256) ? hbuf[p * 65536 + b * 256 + tid]
                             : cbuf[p * 65536 + b * 256 + (tid - 256)];
    __syncthreads();
    {
      float acc = bah_r;
      const float4* hv = (const float4*)&sm.hc[q * 128];
      #pragma unroll
      for (int j = 0; j < 32; ++j) {
        float4 h4 = hv[j];
        acc = fmaf(wreg[4*j],   h4.x, acc);
        acc = fmaf(wreg[4*j+1], h4.y, acc);
        acc = fmaf(wreg[4*j+2], h4.z, acc);
        acc = fmaf(wreg[4*j+3], h4.w, acc);
      }
      sm.part4[q][tp] = acc;
    }
    __syncthreads();
    if (tid < 128) {
      float hp = sm.part4[0][tid] + sm.part4[1][tid] + sm.part4[2][tid] + sm.part4[3][tid];
      sm.P[tid] = __expf(2.f * hp);
    }
    __syncthreads();
    {
      float sp = 0.f;
      #pragma unroll
      for (int i = 0; i < 32; ++i) {
        float pe = fmaf(sm.P[q * 32 + i], e_r, 1.f);
        sp = fmaf(w2a_r[i], __builtin_amdgcn_rcpf(pe), sp);
      }
      sm.part4[q][tp] = sp;
    }
    __syncthreads();
    float sc = 0.f, exv = 0.f;
    if (tid < 128) {
      sc = S0 - (sm.part4[0][tid] + sm.part4[1][tid] + sm.part4[2][tid] + sm.part4[3][tid]);
      sm.score[tid] = sc;
    }
    __syncthreads();
    if (tid < 64) {
      float m = fmaxf(sm.score[tid], sm.score[tid + 64]);
      #pragma unroll
      for (int o = 32; o; o >>= 1) m = fmaxf(m, __shfl_xor(m, o));
      if (tid == 0) sm.red[0] = m;
    }
    __syncthreads();
    if (tid < 128) { exv = __expf(sc - sm.red[0]); sm.score[tid] = exv; }
    __syncthreads();
    if (tid < 64) {
      float s = sm.score[tid] + sm.score[tid + 64];
      #pragma unroll
      for (int o = 32; o; o >>= 1) s += __shfl_xor(s, o);
      if (tid == 0) sm.red[1] = s;
    }
    __syncthreads();
    if (tid < 128) {
      float attn = exv / sm.red[1];
      float wx = attn * x[b * (NT * NSER) + t * NSER + tid];
      wxbuf[b * NSER + tid] = wx;
      out_iw[b * (NT * NSER) + t * NSER + tid] = wx;
    }
    gridbar(ctrl, ep); ep++;

    // ================= Phase B: gates + LSTM for (btile, ktile) =================
    #pragma unroll
    for (int it = 0; it < 8; ++it) {
      int el = it * NTHR + tid;
      sm.wx_s[el >> 7][el & 127] = wxbuf[base_b * NSER + el];
    }
    #pragma unroll
    for (int it = 0; it < 16; ++it) {
      int el = it * NTHR + tid;
      sm.h_s[el >> 8][el & 255] = hbuf[p * 65536 + base_b * 256 + el];
    }
    __syncthreads();
    {
      float a0, a1, a2, a3;
      if (half == 0) { a0 = bsum4[0]; a1 = bsum4[1]; a2 = bsum4[2]; a3 = bsum4[3]; }
      else           { a0 = a1 = a2 = a3 = 0.f; }
      const float* __restrict__ w0 = sm.WB[kk];
      const float* __restrict__ w1 = sm.WB[8 + kk];
      const float* __restrict__ w2 = sm.WB[16 + kk];
      const float* __restrict__ w3 = sm.WB[24 + kk];
      const float* __restrict__ vx = sm.wx_s[b2];
      const float* __restrict__ vh = sm.h_s[b2];
#define DOT4(VREF, WOFF) { \
        float4 v = *(const float4*)&(VREF); \
        float4 u0 = *(const float4*)&w0[WOFF]; \
        float4 u1 = *(const float4*)&w1[WOFF]; \
        float4 u2 = *(const float4*)&w2[WOFF]; \
        float4 u3 = *(const float4*)&w3[WOFF]; \
        a0 += v.x*u0.x + v.y*u0.y + v.z*u0.z + v.w*u0.w; \
        a1 += v.x*u1.x + v.y*u1.y + v.z*u1.z + v.w*u1.w; \
        a2 += v.x*u2.x + v.y*u2.y + v.z*u2.z + v.w*u2.w; \
        a3 += v.x*u3.x + v.y*u3.y + v.z*u3.z + v.w*u3.w; }
      if (half == 0) {
        #pragma unroll 8
        for (int c = 0; c < 128; c += 4) DOT4(vx[c], c)
        #pragma unroll 8
        for (int c = 0; c < 64; c += 4) DOT4(vh[c], 128 + c)
      } else {
        #pragma unroll 8
        for (int c = 64; c < 256; c += 4) DOT4(vh[c], 128 + c)
      }
#undef DOT4
      sm.gpart[half][b2][kk][0] = a0;
      sm.gpart[half][b2][kk][1] = a1;
      sm.gpart[half][b2][kk][2] = a2;
      sm.gpart[half][b2][kk][3] = a3;
    }
    __syncthreads();
    if (tid < 256) {
      const int bb = tid & 31, kx = tid >> 5;
      const int gb = base_b + bb, k = k0 + kx;
      float gi = sm.gpart[0][bb][kx][0] + sm.gpart[1][bb][kx][0];
      float gf = sm.gpart[0][bb][kx][1] + sm.gpart[1][bb][kx][1];
      float gg = sm.gpart[0][bb][kx][2] + sm.gpart[1][bb][kx][2];
      float go = sm.gpart[0][bb][kx][3] + sm.gpart[1][bb][kx][3];
      float ii = 1.f / (1.f + __expf(-gi));
      float ff = 1.f / (1.f + __expf(-gf));
      float eg = __expf(2.f * gg);
      float gt = 1.f - 2.f / (eg + 1.f);
      float oo = 1.f / (1.f + __expf(-go));
      float cold = cbuf[p * 65536 + gb * 256 + k];
      float c2 = ff * cold + ii * gt;
      float ec = __expf(2.f * c2);
      float tc = 1.f - 2.f / (ec + 1.f);
      float h2 = oo * tc;
      cbuf[p2 * 65536 + gb * 256 + k] = c2;
      hbuf[p2 * 65536 + gb * 256 + k] = h2;
      out_ie[gb * (NT * NH) + t * NH + k] = h2;
    }
    if (t != NT - 1) { gridbar(ctrl, ep); ep++; }
  }
}

extern "C" void kernel_launch(void* const* d_in, const int* in_sizes, int n_in,
                              void* d_out, int out_size, void* d_ws, size_t ws_size,
                              hipStream_t stream) {
  const float* x    = (const float*)d_in[0];
  const float* W_ah = (const float*)d_in[1];
  const float* b_ah = (const float*)d_in[2];
  const float* W_ai = (const float*)d_in[3];
  const float* b_ai = (const float*)d_in[4];
  const float* W_a  = (const float*)d_in[5];
  const float* b_a  = (const float*)d_in[6];
  const float* W_ih = (const float*)d_in[7];
  const float* W_hh = (const float*)d_in[8];
  const float* b_ih = (const float*)d_in[9];
  const float* b_hh = (const float*)d_in[10];
  float* out_iw = (float*)d_out;
  float* out_ie = (float*)d_out + NB * NT * NSER;
  float* ws = (float*)d_ws;

  hipLaunchKernelGGL(enc_init, dim3(256), dim3(256), 0, stream, ws);

  void* args[] = { &x, &W_ah, &b_ah, &W_ai, &b_ai, &W_a, &b_a, &W_ih, &W_hh,
                   &b_ih, &b_hh, &out_iw, &out_ie, &ws };
  hipLaunchCooperativeKernel((void*)enc_main, dim3(NWG), dim3(NTHR), args, 0, stream);
}

// Round 2
// 1189.716 us; speedup vs baseline: 7.4868x; 7.4868x over previous
//
#include <hip/hip_runtime.h>
#include <hip/hip_bf16.h>
#include <cstdint>

#define NBATCH 256
#define NT     128
#define NS     128
#define NHID   256
#define GB     2                 // batch elements per workgroup
#define NWG    (NBATCH / GB)     // 128
#define NTHR   1024

typedef _Float16 f16;
typedef _Float16 f16x2 __attribute__((ext_vector_type(2)));

// ws byte layout
#define WGP_OFF  0         // f16 [48][1024][8]  = 786432 B  (W_ih|W_hh permuted)
#define WAHP_OFF 786432    // f16 [8][1024][8]   = 131072 B  (W_ah permuted)

__device__ __forceinline__ float dot2f(f16x2 a, f16x2 b, float c) {
#if defined(__has_builtin) && __has_builtin(__builtin_amdgcn_fdot2)
  return __builtin_amdgcn_fdot2(a, b, c, false);
#else
  return c + (float)a.x * (float)b.x + (float)a.y * (float)b.y;
#endif
}

// Pre-permute weights into f16 streaming layouts.
// WGP[(j*1024 + r)*8 + e] = row r of [W_ih | W_hh], col j*8+e   (j<48 -> 384 cols)
// WAHP[(i*1024 + t)*8 + e] = W_ah[t>>3][(t&7)*64 + i*8 + e]
__global__ void enc_prep(const float* __restrict__ W_ah, const float* __restrict__ W_ih,
                         const float* __restrict__ W_hh, f16* __restrict__ wgp,
                         f16* __restrict__ wahp) {
  int idx = blockIdx.x * 1024 + threadIdx.x;
  if (idx < 48 * 1024 * 8) {
    int e = idx & 7, row = (idx >> 3) & 1023, j = idx >> 13;
    int col = j * 8 + e;
    float v = (col < 128) ? W_ih[row * 128 + col] : W_hh[row * 256 + (col - 128)];
    wgp[idx] = (f16)v;
  }
  if (idx < 8 * 1024 * 8) {
    int e = idx & 7, t = (idx >> 3) & 1023, i = idx >> 13;
    int row = t >> 3, q = t & 7;
    wahp[idx] = (f16)W_ah[row * 512 + q * 64 + i * 8 + e];
  }
}

struct __align__(16) Sm {
  f16 waht[8][1024][8];       // 131072 B  W_ah resident
  f16 hc16[GB][512];          // 2048      [h|c] f16 per batch elem
  f16 act16[GB][384];         // 1536      [wx(128)|h(256)] f16
  float E[GB][128];           // 1024      exp(2*ipart)
  float P[GB][128];           // 1024      exp(2*hpart)
  float sc[GB][128];          // 1024
  union {
    float spart[4][GB][128];  // 4096
    float gacc[1024][GB];     // 8192
  } u;
  float cbuf[GB][256];        // 2048      c state (fp32)
  float bias[1024];           // 4096      b_ih + b_hh
  float w2a[128];             // 512
  float bah[128];             // 512
  float red[8];
};

__global__ __launch_bounds__(NTHR, 1) void enc_main(
    const float* __restrict__ x,    const float* __restrict__ b_ah_g,
    const float* __restrict__ W_ai, const float* __restrict__ b_ai,
    const float* __restrict__ W_a,  const float* __restrict__ b_a,
    const float* __restrict__ b_ih, const float* __restrict__ b_hh,
    const f16* __restrict__ wgp,    const f16* __restrict__ wahp,
    float* __restrict__ out_iw,     float* __restrict__ out_ie)
{
  __shared__ Sm sm;
  const int tid = threadIdx.x;
  const int b0  = blockIdx.x * GB;

  // ---- init: stage W_ah (flat 128KB copy), biases, constants, zero state ----
  {
    const float4* src = (const float4*)wahp;
    float4* dst = (float4*)sm.waht;
    #pragma unroll
    for (int i = 0; i < 8; ++i) dst[i * NTHR + tid] = src[i * NTHR + tid];
  }
  sm.bias[tid] = b_ih[tid] + b_hh[tid];
  if (tid < 128) { sm.w2a[tid] = 2.f * W_a[tid]; sm.bah[tid] = b_ah_g[tid]; }
  if (tid < 512) sm.cbuf[tid >> 8][tid & 255] = 0.f;
  sm.hc16[tid >> 9][tid & 511] = (f16)0.f;
  if (tid < 768) sm.act16[tid / 384][tid % 384] = (f16)0.f;
  if (tid == 0) { float s = b_a[0]; for (int i = 0; i < 128; ++i) s += W_a[i]; sm.red[0] = s; }

  // ---- ipart -> E (time-invariant) ----
  {
    const int n = tid & 127, bb = (tid >> 7) & 1, tq = tid >> 8;
    const float* xb = x + (size_t)(b0 + bb) * (NT * NS);
    float a = 0.f;
    for (int t = tq * 32; t < tq * 32 + 32; ++t) a += xb[t * NS + n] * W_ai[t];
    sm.u.spart[tq][bb][n] = a;
  }
  __syncthreads();
  if (tid < 256) {
    int bb = tid >> 7, n = tid & 127;
    float ip = sm.u.spart[0][bb][n] + sm.u.spart[1][bb][n] +
               sm.u.spart[2][bb][n] + sm.u.spart[3][bb][n] + b_ai[0];
    sm.E[bb][n] = __expf(2.f * ip);
  }
  __syncthreads();

  const float S0 = sm.red[0];
  const int row8 = tid >> 3, q8 = tid & 7;          // hpart mapping
  const int nn = tid & 127, bb1 = (tid >> 7) & 1, tq4 = tid >> 8;  // score mapping
  const f16* wrow = wgp + (size_t)tid * 8;          // gates: [j][1024][8] stride 8192 f16

  for (int t = 0; t < NT; ++t) {
    // ---------- hpart: P[b][t'] = exp(2*(W_ah[t',:]·hc + b_ah)) ----------
    float hp0 = 0.f, hp1 = 0.f;
    #pragma unroll
    for (int i = 0; i < 8; ++i) {
      int ii = (i + q8) & 7;                         // bank-spread rotation
      float4 wv = *(const float4*)&sm.waht[ii][tid][0];
      const f16x2* wp = (const f16x2*)&wv;
      float4 a0 = *(const float4*)&sm.hc16[0][q8 * 64 + ii * 8];
      float4 a1 = *(const float4*)&sm.hc16[1][q8 * 64 + ii * 8];
      const f16x2* p0 = (const f16x2*)&a0;
      const f16x2* p1 = (const f16x2*)&a1;
      #pragma unroll
      for (int u = 0; u < 4; ++u) {
        hp0 = dot2f(wp[u], p0[u], hp0);
        hp1 = dot2f(wp[u], p1[u], hp1);
      }
    }
    #pragma unroll
    for (int o = 1; o <= 4; o <<= 1) {
      hp0 += __shfl_xor(hp0, o);
      hp1 += __shfl_xor(hp1, o);
    }
    if (q8 == 0) sm.P[0][row8] = __expf(2.f * (hp0 + sm.bah[row8]));
    if (q8 == 1) sm.P[1][row8] = __expf(2.f * (hp1 + sm.bah[row8]));
    __syncthreads();  // s1

    // ---------- score[b][n] = S0 - sum_t' w2a[t'] / (1 + P[t']*E[n]) ----------
    {
      float sp = 0.f;
      const float ev = sm.E[bb1][nn];
      #pragma unroll 8
      for (int tt = tq4 * 32; tt < tq4 * 32 + 32; ++tt) {
        float pe = fmaf(sm.P[bb1][tt], ev, 1.f);
        sp = fmaf(sm.w2a[tt], __builtin_amdgcn_rcpf(pe), sp);
      }
      sm.u.spart[tq4][bb1][nn] = sp;
    }
    __syncthreads();  // s2
    if (tid < 256) {
      int bb = tid >> 7, n = tid & 127;
      sm.sc[bb][n] = S0 - (sm.u.spart[0][bb][n] + sm.u.spart[1][bb][n] +
                           sm.u.spart[2][bb][n] + sm.u.spart[3][bb][n]);
    }
    __syncthreads();  // s3

    // ---------- softmax over n, wx = attn*x_t (waves 0-1 only) ----------
    if (tid < 128) {
      int bb = tid >> 6, l = tid & 63;
      float s0v = sm.sc[bb][l], s1v = sm.sc[bb][l + 64];
      float m = fmaxf(s0v, s1v);
      #pragma unroll
      for (int o = 32; o; o >>= 1) m = fmaxf(m, __shfl_xor(m, o));
      float e0 = __expf(s0v - m), e1 = __expf(s1v - m);
      float s = e0 + e1;
      #pragma unroll
      for (int o = 32; o; o >>= 1) s += __shfl_xor(s, o);
      float r = 1.f / s;
      const float* xb = x + ((size_t)(b0 + bb) * NT + t) * NS;
      float wx0 = e0 * r * xb[l], wx1 = e1 * r * xb[l + 64];
      sm.act16[bb][l] = (f16)wx0;
      sm.act16[bb][l + 64] = (f16)wx1;
      float* ow = out_iw + ((size_t)(b0 + bb) * NT + t) * NS;
      ow[l] = wx0; ow[l + 64] = wx1;
    }
    __syncthreads();  // s4

    // ---------- gates: row tid of [W_ih|W_hh] · [wx|h] per batch elem ----------
    {
      float acc0 = 0.f, acc1 = 0.f;
      float4 wc = *(const float4*)(wrow);
      float4 wn = *(const float4*)(wrow + 8192);
      #pragma unroll 4
      for (int j = 0; j < 48; ++j) {
        int jn = j + 2; if (jn > 47) jn = 47;
        float4 wf = *(const float4*)(wrow + (size_t)jn * 8192);
        const f16x2* wp = (const f16x2*)&wc;
        float4 a0 = *(const float4*)&sm.act16[0][j * 8];
        float4 a1 = *(const float4*)&sm.act16[1][j * 8];
        const f16x2* p0 = (const f16x2*)&a0;
        const f16x2* p1 = (const f16x2*)&a1;
        #pragma unroll
        for (int u = 0; u < 4; ++u) {
          acc0 = dot2f(wp[u], p0[u], acc0);
          acc1 = dot2f(wp[u], p1[u], acc1);
        }
        wc = wn; wn = wf;
      }
      float bs = sm.bias[tid];
      sm.u.gacc[tid][0] = acc0 + bs;
      sm.u.gacc[tid][1] = acc1 + bs;
    }
    __syncthreads();  // s5

    // ---------- LSTM pointwise ----------
    if (tid < 512) {
      int bb = tid >> 8, k = tid & 255;
      float gi = sm.u.gacc[k][bb];
      float gf = sm.u.gacc[256 + k][bb];
      float gg = sm.u.gacc[512 + k][bb];
      float go = sm.u.gacc[768 + k][bb];
      float ii = 1.f / (1.f + __expf(-gi));
      float ff = 1.f / (1.f + __expf(-gf));
      float gt = 1.f - 2.f / (1.f + __expf(2.f * gg));
      float oo = 1.f / (1.f + __expf(-go));
      float c2 = ff * sm.cbuf[bb][k] + ii * gt;
      float h2 = oo * (1.f - 2.f / (1.f + __expf(2.f * c2)));
      sm.cbuf[bb][k] = c2;
      sm.hc16[bb][k] = (f16)h2;
      sm.hc16[bb][256 + k] = (f16)c2;
      sm.act16[bb][128 + k] = (f16)h2;
      out_ie[((size_t)(b0 + bb) * NT + t) * NHID + k] = h2;
    }
    __syncthreads();  // s6
  }
}

extern "C" void kernel_launch(void* const* d_in, const int* in_sizes, int n_in,
                              void* d_out, int out_size, void* d_ws, size_t ws_size,
                              hipStream_t stream) {
  const float* x    = (const float*)d_in[0];
  const float* W_ah = (const float*)d_in[1];
  const float* b_ah = (const float*)d_in[2];
  const float* W_ai = (const float*)d_in[3];
  const float* b_ai = (const float*)d_in[4];
  const float* W_a  = (const float*)d_in[5];
  const float* b_a  = (const float*)d_in[6];
  const float* W_ih = (const float*)d_in[7];
  const float* W_hh = (const float*)d_in[8];
  const float* b_ih = (const float*)d_in[9];
  const float* b_hh = (const float*)d_in[10];
  float* out_iw = (float*)d_out;
  float* out_ie = (float*)d_out + (size_t)NBATCH * NT * NS;

  f16* wgp  = (f16*)((char*)d_ws + WGP_OFF);
  f16* wahp = (f16*)((char*)d_ws + WAHP_OFF);

  hipLaunchKernelGGL(enc_prep, dim3(384), dim3(1024), 0, stream, W_ah, W_ih, W_hh, wgp, wahp);
  hipLaunchKernelGGL(enc_main, dim3(NWG), dim3(NTHR), 0, stream,
                     x, b_ah, W_ai, b_ai, W_a, b_a, b_ih, b_hh, wgp, wahp, out_iw, out_ie);
}